// Round 9
// baseline (130.351 us; speedup 1.0000x reference)
//
#include <hip/hip_runtime.h>
#include <hip/hip_bf16.h>

typedef unsigned short u16;
typedef __attribute__((ext_vector_type(8))) short short8;
typedef __attribute__((ext_vector_type(4))) float f32x4;
typedef __attribute__((ext_vector_type(4))) unsigned int u32x4;

#define CC    128
#define WW    48
#define HW2   2304      // 48*48
#define NHW   46
#define NQ    2116      // 46*46
#define NPIX  2304      // pixels per image
#define SETSZ ((size_t)NPIX * NPIX)   // D elems per candidate set
#define BATCH 2

__device__ __forceinline__ u16 f2bf(float f) {
  union { float f; unsigned u; } x; x.f = f;
  unsigned r = (x.u + 0x7fffu + ((x.u >> 16) & 1u)) >> 16;
  return (u16)r;
}
__device__ __forceinline__ float b2f(u16 v) {
  union { unsigned u; float f; } x; x.u = ((unsigned)v) << 16;
  return x.f;
}

// ---- kernel 1: per-pixel normalize + transpose to [pix][128c] bf16, chunk-swizzled ----
__global__ __launch_bounds__(256) void k_norm(const float* __restrict__ pred,
                                              const float* __restrict__ targ,
                                              u16* __restrict__ PnT, u16* __restrict__ TnT) {
  const int img = blockIdx.y;          // 0..5 : 0-1 pred, 2-5 target
  const int p0  = blockIdx.x * 64;     // 36 blocks of 64 pixels
  const int tid = threadIdx.x;
  const float* src = img < 2 ? pred + (size_t)img * CC * HW2
                             : targ + (size_t)(img - 2) * CC * HW2;
  u16* out = img < 2 ? PnT + (size_t)img * NPIX * CC
                     : TnT + (size_t)(img - 2) * NPIX * CC;

  __shared__ float sT[64][129];
  __shared__ float sInv[64];

  #pragma unroll
  for (int it = 0; it < 32; ++it) {
    int idx = it * 256 + tid;
    int c = idx >> 6, p = idx & 63;
    sT[p][c] = src[(size_t)c * HW2 + p0 + p];
  }
  __syncthreads();
  if (tid < 64) {
    float s = 0.f;
    for (int c = 0; c < CC; ++c) { float v = sT[tid][c]; s += v * v; }
    sInv[tid] = 1.0f / fmaxf(sqrtf(s), 1e-12f);
  }
  __syncthreads();
  #pragma unroll
  for (int it = 0; it < 4; ++it) {
    int cid = it * 256 + tid;
    int p = cid >> 4, g = cid & 15;
    int r = p0 + p;
    int sc = (g & ~7) | ((g & 7) ^ (r & 7));
    float inv = sInv[p];
    unsigned pack[4];
    #pragma unroll
    for (int e = 0; e < 8; ++e) {
      float v = sT[p][sc * 8 + e] * inv;
      if ((e & 1) == 0) pack[e >> 1] = (unsigned)f2bf(v);
      else              pack[e >> 1] |= ((unsigned)f2bf(v)) << 16;
    }
    u32x4 o; o.x = pack[0]; o.y = pack[1]; o.z = pack[2]; o.w = pack[3];
    *reinterpret_cast<u32x4*>(out + (size_t)r * CC + g * 8) = o;
  }
}

// ---- kernel 2: pixel-dot GEMM D[s] = Pn[b] . Tn[b*2+s]^T, output in 48x48-block layout ----
// D element (row,col) stored at ((row/48)*48 + col/48)*2304 + (row%48)*48 + (col%48):
// each 48x48 block is 4.6 KB contiguous -> k_stencil stages blocks with coalesced reads.
__global__ __launch_bounds__(512) void k_pixdot(const u16* __restrict__ PnT, const u16* __restrict__ TnT,
                                                u16* __restrict__ D, int b) {
  __shared__ u16 sA[128 * 128];        // 32 KB = 2048 16B slots
  __shared__ u16 sB[256 * 128];        // 64 KB = 4096 16B slots
  const int nt = blockIdx.x, mt = blockIdx.y, s = blockIdx.z;
  const int tid = threadIdx.x, lane = tid & 63, wid = tid >> 6;
  const int wm = wid >> 2, wn = wid & 3;
  const int r15 = lane & 15, g16 = lane >> 4;

  const u16* Ab = PnT + (size_t)b * NPIX * CC + (size_t)mt * 128 * CC;
  const u16* Bb = TnT + (size_t)(b * 2 + s) * NPIX * CC + (size_t)nt * 256 * CC;
  u16* Dset = D + (size_t)s * SETSZ;

  #pragma unroll
  for (int i = 0; i < 4; ++i) {
    int sl = i * 512 + tid;
    __builtin_amdgcn_global_load_lds(
      (const __attribute__((address_space(1))) unsigned*)(Ab + (size_t)(sl >> 4) * CC + (sl & 15) * 8),
      (__attribute__((address_space(3))) unsigned*)&sA[sl * 8], 16, 0, 0);
  }
  #pragma unroll
  for (int i = 0; i < 8; ++i) {
    int sl = i * 512 + tid;
    __builtin_amdgcn_global_load_lds(
      (const __attribute__((address_space(1))) unsigned*)(Bb + (size_t)(sl >> 4) * CC + (sl & 15) * 8),
      (__attribute__((address_space(3))) unsigned*)&sB[sl * 8], 16, 0, 0);
  }

  f32x4 acc[4][4];
  const f32x4 z4 = {0.f, 0.f, 0.f, 0.f};
  #pragma unroll
  for (int i = 0; i < 4; ++i)
    #pragma unroll
    for (int j = 0; j < 4; ++j) acc[i][j] = z4;

  asm volatile("s_waitcnt vmcnt(0)" ::: "memory");
  __builtin_amdgcn_s_barrier();

  const int arow0 = wm * 64 + r15;
  const int brow0 = wn * 64 + r15;
  #pragma unroll
  for (int ks = 0; ks < 4; ++ks) {
    const int c = ks * 4 + g16;
    short8 af[4], bfv[4];
    #pragma unroll
    for (int mi = 0; mi < 4; ++mi) {
      int row = arow0 + mi * 16;
      af[mi] = *reinterpret_cast<const short8*>(
        &sA[row * 128 + (c >> 3) * 64 + (((c & 7) ^ (row & 7)) * 8)]);
    }
    #pragma unroll
    for (int ni = 0; ni < 4; ++ni) {
      int row = brow0 + ni * 16;
      bfv[ni] = *reinterpret_cast<const short8*>(
        &sB[row * 128 + (c >> 3) * 64 + (((c & 7) ^ (row & 7)) * 8)]);
    }
    __builtin_amdgcn_s_setprio(1);
    #pragma unroll
    for (int mi = 0; mi < 4; ++mi)
      #pragma unroll
      for (int ni = 0; ni < 4; ++ni)
        acc[mi][ni] = __builtin_amdgcn_mfma_f32_16x16x32_bf16(af[mi], bfv[ni], acc[mi][ni], 0, 0, 0);
    __builtin_amdgcn_s_setprio(0);
  }

  const int m0 = mt * 128 + wm * 64, n0 = nt * 256 + wn * 64;
  #pragma unroll
  for (int mi = 0; mi < 4; ++mi)
    #pragma unroll
    for (int ni = 0; ni < 4; ++ni)
      #pragma unroll
      for (int rg = 0; rg < 4; ++rg) {
        int row = m0 + mi * 16 + g16 * 4 + rg;
        int col = n0 + ni * 16 + r15;
        int rb = row / 48, u = row - rb * 48;
        int cb = col / 48, v = col - cb * 48;
        Dset[(size_t)(rb * 48 + cb) * HW2 + u * 48 + v] = f2bf(acc[mi][ni][rg]);
      }
}

// ---- kernel 3: blocked 9-tap stencil + per-(qx, ny-chunk) argmax partials ----
// block = (qy, ny-chunk of 6); per (kc, ny): stage 3 contiguous 48x48 D-blocks
// (M_di = Dblk[qy+di][ny+di]), compute S(qx,nx) = sum_{di,dj} M_di[qx+dj][nx+dj].
__global__ __launch_bounds__(256) void k_stencil(const u16* __restrict__ D,
                                                 float* __restrict__ pval, u16* __restrict__ pidx,
                                                 int b) {
  const int qy = blockIdx.x;        // 0..45
  const int nyc = blockIdx.y;       // 0..7  (ny = nyc*6 + j, j<6, ny<46)
  const int tid = threadIdx.x, lane = tid & 63, w = tid >> 6;

  __shared__ u16 sM[2][7040];       // 2 x (3*2304 + pad for harmless lane-tail reads)

  float best[12]; int bidx[12];
  #pragma unroll
  for (int s = 0; s < 12; ++s) { best[s] = -3.0e38f; bidx[s] = 0x7fffffff; }
  const int qx0 = w * 12;

  auto stage = [&](int buf, int kc, int ny) {
    const u16* Dset = D + (size_t)kc * SETSZ;
    #pragma unroll
    for (int i = 0; i < 3; ++i) {
      int sl = i * 256 + tid;
      int di = sl >= 576 ? 2 : (sl >= 288 ? 1 : 0);
      int off = sl - di * 288;
      const u16* src = Dset + (size_t)((qy + di) * 48 + (ny + di)) * HW2 + off * 8;
      __builtin_amdgcn_global_load_lds((const __attribute__((address_space(1))) unsigned*)src,
        (__attribute__((address_space(3))) unsigned*)&sM[buf][sl * 8], 16, 0, 0);
    }
    if (tid < 96) {
      int sl = 768 + tid;
      const u16* src = Dset + (size_t)((qy + 2) * 48 + (ny + 2)) * HW2 + (sl - 576) * 8;
      __builtin_amdgcn_global_load_lds((const __attribute__((address_space(1))) unsigned*)src,
        (__attribute__((address_space(3))) unsigned*)&sM[buf][sl * 8], 16, 0, 0);
    }
  };

  stage(0, 0, nyc * 6);
  asm volatile("s_waitcnt vmcnt(0)" ::: "memory");
  __builtin_amdgcn_s_barrier();

  for (int it = 0; it < 12; ++it) {
    const int buf = it & 1;
    const int kc = it / 6, j = it - kc * 6;
    const int ny = nyc * 6 + j;
    if (it + 1 < 12) {
      int kc1 = (it + 1) / 6, ny1 = nyc * 6 + (it + 1) - kc1 * 6;
      if (ny1 < NHW) stage(buf ^ 1, kc1, ny1);
    }
    if (ny < NHW) {
      #pragma unroll
      for (int s = 0; s < 12; ++s) {
        int qx = qx0 + s;
        float sc = 0.f;
        #pragma unroll
        for (int di = 0; di < 3; ++di)
          #pragma unroll
          for (int dj = 0; dj < 3; ++dj)
            sc += b2f(sM[buf][di * HW2 + (qx + dj) * 48 + lane + dj]);
        int n = kc * NQ + ny * NHW + lane;
        bool take = (lane < NHW) && (qx < NHW) &&
                    ((sc > best[s]) || (sc == best[s] && n < bidx[s]));
        best[s] = take ? sc : best[s];
        bidx[s] = take ? n : bidx[s];
      }
    }
    asm volatile("s_waitcnt vmcnt(0)" ::: "memory");
    __builtin_amdgcn_s_barrier();
  }

  #pragma unroll
  for (int s = 0; s < 12; ++s) {
    float bv = best[s]; int bi = bidx[s];
    #pragma unroll
    for (int off = 1; off < 64; off <<= 1) {
      float ov = __shfl_xor(bv, off, 64);
      int   oi = __shfl_xor(bi, off, 64);
      bool take = (ov > bv) || (ov == bv && oi < bi);
      bv = take ? ov : bv; bi = take ? oi : bi;
    }
    if (lane == 0) {
      size_t o = ((size_t)(b * NHW + qy) * 48 + (qx0 + s)) * 8 + nyc;
      pval[o] = bv;
      pidx[o] = (u16)(bi & 0xffff);
    }
  }
}

// ---- kernel 4: wave-per-query reduce of 8 ny-chunk partials + raw-patch MSE ----
__global__ __launch_bounds__(256) void k_red(const float* __restrict__ pval, const u16* __restrict__ pidx,
                                             const float* __restrict__ pred, const float* __restrict__ targ,
                                             float* __restrict__ msep) {
  int gw = (blockIdx.x * 256 + threadIdx.x) >> 6;
  int lane = threadIdx.x & 63;
  if (gw >= BATCH * NQ) return;
  int b = gw >= NQ ? 1 : 0;
  int q = gw - b * NQ;
  int qy = q / NHW, qx = q - qy * NHW;

  size_t base = ((size_t)(b * NHW + qy) * 48 + qx) * 8;
  float bv = -3.0e38f; int bi = 0x7fffffff;
  if (lane < 8) { bv = pval[base + lane]; bi = pidx[base + lane]; }
  #pragma unroll
  for (int off = 1; off < 64; off <<= 1) {
    float ov = __shfl_xor(bv, off, 64);
    int   oi = __shfl_xor(bi, off, 64);
    bool take = (ov > bv) || (ov == bv && oi < bi);
    bv = take ? ov : bv; bi = take ? oi : bi;
  }
  int kc = bi >= NQ ? 1 : 0;
  int ns = bi - kc * NQ;
  ns = ns < NQ ? ns : NQ - 1;
  int ny = ns / NHW, nx = ns - ny * NHW;

  const float* P = pred + (size_t)b * CC * HW2;
  const float* T = targ + (size_t)(b * 2 + kc) * CC * HW2;
  float ssum = 0.f;
  for (int i = lane; i < CC * 9; i += 64) {
    int c = i / 9, sp = i - 9 * c;
    int di = sp / 3, dj = sp - 3 * di;
    float d = P[(size_t)c * HW2 + (qy + di) * WW + qx + dj]
            - T[(size_t)c * HW2 + (ny + di) * WW + nx + dj];
    ssum += d * d;
  }
  #pragma unroll
  for (int off = 1; off < 64; off <<= 1) ssum += __shfl_xor(ssum, off, 64);
  if (lane == 0) msep[gw] = ssum;
}

// ---- kernel 5: final deterministic reduction ----
__global__ void k_final(const float* __restrict__ msep, float* __restrict__ out) {
  int t = threadIdx.x;
  float s = 0.f;
  for (int i = t; i < BATCH * NQ; i += 256) s += msep[i];
  __shared__ float red[256];
  red[t] = s; __syncthreads();
  for (int st = 128; st > 0; st >>= 1) { if (t < st) red[t] += red[t + st]; __syncthreads(); }
  if (t == 0) out[0] = red[0] * (1.0f / 4875264.0f);   // 2*2116*128*9
}

extern "C" void kernel_launch(void* const* d_in, const int* in_sizes, int n_in,
                              void* d_out, int out_size, void* d_ws, size_t ws_size,
                              hipStream_t stream) {
  const float* pred = (const float*)d_in[0];
  const float* targ = (const float*)d_in[1];
  char* ws = (char*)d_ws;

  size_t offP  = 0;
  size_t offT  = offP  + (size_t)2 * NPIX * CC * 2;        // PnT: 1,179,648
  size_t offD  = offT  + (size_t)4 * NPIX * CC * 2;        // TnT: 2,359,296
  size_t offPv = offD  + (size_t)2 * SETSZ * 2;            // D (2 sets): 21,233,664
  size_t offPi = offPv + (size_t)2 * NHW * 48 * 8 * 4;     // pval: 141,312
  size_t offM  = offPi + (size_t)2 * NHW * 48 * 8 * 2;     // pidx: 70,656

  u16*   PnT  = (u16*)(ws + offP);
  u16*   TnT  = (u16*)(ws + offT);
  u16*   Dbuf = (u16*)(ws + offD);
  float* pval = (float*)(ws + offPv);
  u16*   pidx = (u16*)(ws + offPi);
  float* msep = (float*)(ws + offM);                       // total ~25 MB

  k_norm<<<dim3(36, 6), 256, 0, stream>>>(pred, targ, PnT, TnT);
  k_pixdot<<<dim3(9, 18, 2), 512, 0, stream>>>(PnT, TnT, Dbuf, 0);
  k_stencil<<<dim3(NHW, 8), 256, 0, stream>>>(Dbuf, pval, pidx, 0);
  k_pixdot<<<dim3(9, 18, 2), 512, 0, stream>>>(PnT, TnT, Dbuf, 1);
  k_stencil<<<dim3(NHW, 8), 256, 0, stream>>>(Dbuf, pval, pidx, 1);
  k_red<<<dim3((BATCH * NQ + 3) / 4), 256, 0, stream>>>(pval, pidx, pred, targ, msep);
  k_final<<<1, 256, 0, stream>>>(msep, (float*)d_out);
}